// Round 9
// baseline (185.758 us; speedup 1.0000x reference)
//
#include <hip/hip_runtime.h>
#include <hip/hip_bf16.h>

#define BN 4
#define CC 256
#define C8 32
#define NN 4096
#define PROJ_ROWS 320
#define LOG2E 1.4426950408889634f

typedef __attribute__((ext_vector_type(8))) short short8;
typedef __attribute__((ext_vector_type(4))) float f32x4;

__device__ __forceinline__ unsigned short f2bf(float f) {
    unsigned u = __builtin_bit_cast(unsigned, f);
    unsigned r = (u + 0x7fffu + ((u >> 16) & 1u)) >> 16;
    return (unsigned short)r;
}
// pack two fp32 -> two bf16 in one dword (v_cvt_pk_bf16_f32 on gfx950)
__device__ __forceinline__ unsigned pk2bf(float a, float b) {
#if __has_builtin(__builtin_amdgcn_cvt_pk_bf16_f32)
    auto v = __builtin_amdgcn_cvt_pk_bf16_f32(a, b);
    return __builtin_bit_cast(unsigned, v);
#else
    return (unsigned)f2bf(a) | ((unsigned)f2bf(b) << 16);
#endif
}
__device__ __forceinline__ float bfhi2f(unsigned u) { return __builtin_bit_cast(float, u & 0xffff0000u); }
__device__ __forceinline__ float bflo2f(unsigned u) { return __builtin_bit_cast(float, u << 16); }

// ---------------------------------------------------------------------------
// W pre-cast: Wbf[o 320][c 256] bf16, k-rows (32..63) pre-scaled by log2(e).
// ---------------------------------------------------------------------------
__global__ __launch_bounds__(256) void wcast_kernel(
    const float* __restrict__ Wq, const float* __restrict__ Wk,
    const float* __restrict__ Wv, unsigned short* __restrict__ Wbf)
{
    int o = blockIdx.x, c = threadIdx.x;
    float v;
    if (o < 32)      v = Wq[(size_t)o * CC + c];
    else if (o < 64) v = Wk[(size_t)(o - 32) * CC + c] * LOG2E;
    else             v = Wv[(size_t)(o - 64) * CC + c];
    Wbf[(size_t)o * CC + c] = f2bf(v);
}

// ---------------------------------------------------------------------------
// Projection GEMM (R8, known-good). Block = (b, 32-n tile), all 320 o-rows.
// ---------------------------------------------------------------------------
__global__ __launch_bounds__(256) void proj_kernel(
    const float* __restrict__ x,
    const unsigned short* __restrict__ Wbf,
    const float* __restrict__ bq, const float* __restrict__ bk,
    const float* __restrict__ bv,
    unsigned short* __restrict__ proj, unsigned short* __restrict__ qT)
{
    int bid = blockIdx.x;
    int b = bid >> 7, nt = bid & 127;
    int n0 = nt * 32;
    int tid = threadIdx.x;
    int w = tid >> 6, l = tid & 63, l15 = l & 15, lq = l >> 4;

    __shared__ alignas(16) unsigned short Xt[32][264];

    int c_l = tid >> 3;
    int nb  = (tid & 7) * 4;

#pragma unroll
    for (int kc = 0; kc < 8; kc++) {
        const float* xp = x + ((size_t)(b * CC + kc * 32 + c_l)) * NN + n0 + nb;
        float4 x0 = *(const float4*)xp;
        Xt[nb + 0][kc * 32 + c_l] = f2bf(x0.x);
        Xt[nb + 1][kc * 32 + c_l] = f2bf(x0.y);
        Xt[nb + 2][kc * 32 + c_l] = f2bf(x0.z);
        Xt[nb + 3][kc * 32 + c_l] = f2bf(x0.w);
    }
    __syncthreads();

    f32x4 acc[5][2];
#pragma unroll
    for (int gi = 0; gi < 5; gi++)
#pragma unroll
        for (int mi = 0; mi < 2; mi++) acc[gi][mi] = (f32x4){0.f, 0.f, 0.f, 0.f};

    for (int kc = 0; kc < 8; kc++) {
        short8 af[5];
#pragma unroll
        for (int gi = 0; gi < 5; gi++) {
            int og = (w * 5 + gi) * 16 + l15;
            af[gi] = *(const short8*)(Wbf + (size_t)og * CC + kc * 32 + lq * 8);
        }
#pragma unroll
        for (int gi = 0; gi < 5; gi++) {
#pragma unroll
            for (int mi = 0; mi < 2; mi++) {
                short8 bf = *(const short8*)&Xt[mi * 16 + l15][kc * 32 + lq * 8];
                acc[gi][mi] = __builtin_amdgcn_mfma_f32_16x16x32_bf16(af[gi], bf, acc[gi][mi], 0, 0, 0);
            }
        }
    }

#pragma unroll
    for (int gi = 0; gi < 5; gi++) {
#pragma unroll
        for (int r = 0; r < 4; r++) {
            int og = (w * 5 + gi) * 16 + lq * 4 + r;
            float bias = (og < 32) ? bq[og]
                       : (og < 64) ? bk[og - 32] * LOG2E
                                   : bv[og - 64];
#pragma unroll
            for (int mi = 0; mi < 2; mi++) {
                int n = n0 + mi * 16 + l15;
                unsigned short v16 = f2bf(acc[gi][mi][r] + bias);
                if (og < 32) {
                    qT[((size_t)b * NN + n) * C8 + og] = v16;
                } else {
                    proj[((size_t)b * PROJ_ROWS + og) * NN + n] = v16;
                }
            }
        }
    }
}

// ---------------------------------------------------------------------------
// Flash attention over the query axis (softmax over n; shift-invariant so no
// max subtraction; k pre-scaled by log2e -> raw v_exp_f32).
// R9 loop order (head-exp): after the barrier, IMMEDIATELY compute
// S_{it+1} -> exp -> write ps[(it+1)&1] (WAR-safe: that buffer's readers
// finished in it-1, cleared by this barrier). Its latency is then covered by
// this iteration's PV MFMAs instead of being serially exposed before the
// next barrier. q and av are register-prefetched one iteration ahead.
// ---------------------------------------------------------------------------
template<int NSPLIT, bool FINAL>
__global__ __launch_bounds__(256, 4) void attn_kernel(
    const unsigned short* __restrict__ proj,
    const unsigned short* __restrict__ qT,
    const float* __restrict__ x,
    const float* __restrict__ gamma_p,
    float* __restrict__ out,
    unsigned short* __restrict__ Opart,
    float* __restrict__ Lpart)
{
    constexpr int ITERS = 64 / NSPLIT;
    int bid = blockIdx.x;
    int low = bid & 255;
    int xcd = low & 7;
    int b = xcd >> 1;
    int mtile = ((low >> 3) << 1) | (xcd & 1);
    int m0 = mtile * 64;
    int ch = (bid >> 8) & 1;
    int h  = bid >> 9;
    int nbase = h * (ITERS * 64);

    int tid = threadIdx.x;
    int w = tid >> 6, l = tid & 63, l15 = l & 15, lq = l >> 4;
    int cw = ch * 128 + w * 32;   // this wave's c base (32 c rows)

    __shared__ alignas(16) unsigned short ps[2][64][72];  // [buf][m][n]
    __shared__ float red[4][64];
    __shared__ float Ltot[64];

    const unsigned short* kbase = proj + ((size_t)b * PROJ_ROWS + C8) * NN;
    const unsigned short* vbase = proj + ((size_t)b * PROJ_ROWS + 64) * NN;
    const unsigned short* qbase = qT + (size_t)b * NN * C8;

    // k B-operand fragments: lane = k[c8=lq*8+j][m = m0+mi*16+l15]
    short8 kfrag[4];
#pragma unroll
    for (int mi = 0; mi < 4; mi++) {
        int col = m0 + mi * 16 + l15;
        unsigned short t8[8] __attribute__((aligned(16)));
#pragma unroll
        for (int j = 0; j < 8; j++)
            t8[j] = kbase[(size_t)(lq * 8 + j) * NN + col];
        kfrag[mi] = *(const short8*)t8;
    }

    f32x4 O[2][4];
#pragma unroll
    for (int ci = 0; ci < 2; ci++)
#pragma unroll
        for (int mi = 0; mi < 4; mi++) O[ci][mi] = (f32x4){0.f, 0.f, 0.f, 0.f};
    f32x4 runS[4];
#pragma unroll
    for (int mi = 0; mi < 4; mi++) runS[mi] = (f32x4){0.f, 0.f, 0.f, 0.f};

    // prologue: avc = V chunk 0; S_0 -> exp -> ps[0]; qc = q chunk 1
    short8 avc[2][2];
#pragma unroll
    for (int kh = 0; kh < 2; kh++)
#pragma unroll
        for (int ci = 0; ci < 2; ci++)
            avc[kh][ci] = *(const short8*)(vbase
                + (size_t)(cw + ci * 16 + l15) * NN + nbase + kh * 32 + lq * 8);
    {
        short8 q0 = *(const short8*)(qbase + (size_t)(nbase + 16 * w + l15) * C8 + lq * 8);
#pragma unroll
        for (int mi = 0; mi < 4; mi++) {
            f32x4 S = __builtin_amdgcn_mfma_f32_16x16x32_bf16(
                q0, kfrag[mi], (f32x4){0.f, 0.f, 0.f, 0.f}, 0, 0, 0);
            f32x4 P;
#pragma unroll
            for (int j = 0; j < 4; j++) P[j] = __builtin_amdgcn_exp2f(S[j]);
            runS[mi] += P;
            *(uint2*)&ps[0][mi * 16 + l15][16 * w + lq * 4]
                = make_uint2(pk2bf(P[0], P[1]), pk2bf(P[2], P[3]));
        }
    }
    short8 qc = *(const short8*)(qbase + (size_t)(nbase + 64 + 16 * w + l15) * C8 + lq * 8);

    for (int it = 0; it < ITERS; it++) {
        int n0c = nbase + it * 64;
        __syncthreads();  // ps[it&1] visible; ps[(it+1)&1] WAR cleared

        // HEAD: S_{it+1} -> exp -> write ps[(it+1)&1] (latency covered by PV)
        if (it + 1 < ITERS) {
            unsigned short* pdst = &ps[(it + 1) & 1][0][0];
#pragma unroll
            for (int mi = 0; mi < 4; mi++) {
                f32x4 S = __builtin_amdgcn_mfma_f32_16x16x32_bf16(
                    qc, kfrag[mi], (f32x4){0.f, 0.f, 0.f, 0.f}, 0, 0, 0);
                f32x4 P;
#pragma unroll
                for (int j = 0; j < 4; j++) P[j] = __builtin_amdgcn_exp2f(S[j]);
                runS[mi] += P;
                *(uint2*)(pdst + (mi * 16 + l15) * 72 + 16 * w + lq * 4)
                    = make_uint2(pk2bf(P[0], P[1]), pk2bf(P[2], P[3]));
            }
        }

        // prefetch av (it+1) and q (it+2) — consumed next iteration
        short8 avn[2][2];
        short8 qn;
        if (it + 1 < ITERS) {
            int nn = n0c + 64;
#pragma unroll
            for (int kh = 0; kh < 2; kh++)
#pragma unroll
                for (int ci = 0; ci < 2; ci++)
                    avn[kh][ci] = *(const short8*)(vbase
                        + (size_t)(cw + ci * 16 + l15) * NN + nn + kh * 32 + lq * 8);
            if (it + 2 < ITERS)
                qn = *(const short8*)(qbase + (size_t)(nn + 64 + 16 * w + l15) * C8 + lq * 8);
        }

        // PV: O[c,m] += V[c,n] . P[n,m] from ps[it&1]
        const unsigned short* psrc = &ps[it & 1][0][0];
#pragma unroll
        for (int kh = 0; kh < 2; kh++) {
            short8 bfr[4];
#pragma unroll
            for (int mi = 0; mi < 4; mi++)
                bfr[mi] = *(const short8*)(psrc + (mi * 16 + l15) * 72 + kh * 32 + lq * 8);
#pragma unroll
            for (int ci = 0; ci < 2; ci++)
#pragma unroll
                for (int mi = 0; mi < 4; mi++)
                    O[ci][mi] = __builtin_amdgcn_mfma_f32_16x16x32_bf16(
                        avc[kh][ci], bfr[mi], O[ci][mi], 0, 0, 0);
        }

        if (it + 1 < ITERS) {
#pragma unroll
            for (int kh = 0; kh < 2; kh++)
#pragma unroll
                for (int ci = 0; ci < 2; ci++) avc[kh][ci] = avn[kh][ci];
            qc = qn;
        }
    }

    // column sums: in-lane, cross-lane (row quads), then cross-wave via LDS
#pragma unroll
    for (int mi = 0; mi < 4; mi++) {
        float s = (runS[mi][0] + runS[mi][1]) + (runS[mi][2] + runS[mi][3]);
        s += __shfl_xor(s, 16);
        s += __shfl_xor(s, 32);
        red[w][mi * 16 + l15] = s;
    }
    __syncthreads();
    if (tid < 64) Ltot[tid] = red[0][tid] + red[1][tid] + red[2][tid] + red[3][tid];
    __syncthreads();

    if constexpr (FINAL) {
        float gamma = gamma_p[0];
        float iv[4];
#pragma unroll
        for (int mi = 0; mi < 4; mi++) iv[mi] = 1.0f / Ltot[mi * 16 + l15];
#pragma unroll
        for (int ci = 0; ci < 2; ci++) {
#pragma unroll
            for (int mi = 0; mi < 4; mi++) {
                int m = m0 + mi * 16 + l15;
#pragma unroll
                for (int r = 0; r < 4; r++) {
                    int c = cw + ci * 16 + lq * 4 + r;
                    size_t idx = ((size_t)b * CC + c) * NN + m;
                    out[idx] = gamma * (O[ci][mi][r] * iv[mi]) + x[idx];
                }
            }
        }
    } else {
        size_t p = ((size_t)h * BN + b) * 64 + mtile;
        if (ch == 0 && tid < 64) Lpart[p * 64 + tid] = Ltot[tid];
        // Opart layout [p][m 64][c 256] bf16
        unsigned short* Ob = Opart + p * (size_t)(64 * 256);
#pragma unroll
        for (int ci = 0; ci < 2; ci++) {
#pragma unroll
            for (int mi = 0; mi < 4; mi++) {
                *(uint2*)(Ob + (size_t)(mi * 16 + l15) * 256 + cw + ci * 16 + lq * 4)
                    = make_uint2(pk2bf(O[ci][mi][0], O[ci][mi][1]),
                                 pk2bf(O[ci][mi][2], O[ci][mi][3]));
            }
        }
    }
}

// ---------------------------------------------------------------------------
// Combine: out = gamma * (sum_h O_h) / (sum_h L_h) + x. Opart bf16 [m][c].
// Grid 1024 = (b, mt, c-quarter); LDS transpose for coalesced out writes.
// ---------------------------------------------------------------------------
template<int NSPLIT>
__global__ __launch_bounds__(256) void combine_kernel(
    const unsigned short* __restrict__ Opart, const float* __restrict__ Lpart,
    const float* __restrict__ x, const float* __restrict__ gamma_p,
    float* __restrict__ out)
{
    int bid = blockIdx.x;
    int cq = bid & 3;
    int mt = (bid >> 2) & 63;
    int b  = bid >> 8;
    int tid = threadIdx.x;
    float gamma = gamma_p[0];

    __shared__ float trans[64][65];

    int m  = tid >> 2;
    int cg = (tid & 3) * 16;

    float Ls = 0.f;
#pragma unroll
    for (int hh = 0; hh < NSPLIT; hh++)
        Ls += Lpart[(((size_t)hh * BN + b) * 64 + mt) * 64 + m];
    float scale = gamma / Ls;

    float acc[16];
#pragma unroll
    for (int j = 0; j < 16; j++) acc[j] = 0.f;
#pragma unroll
    for (int hh = 0; hh < NSPLIT; hh++) {
        const unsigned short* row = Opart
            + (((size_t)hh * BN + b) * 64 + mt) * (size_t)(64 * 256)
            + (size_t)m * 256 + cq * 64 + cg;
#pragma unroll
        for (int j4 = 0; j4 < 4; j4++) {
            uint2 u = *(const uint2*)(row + j4 * 4);
            acc[j4 * 4 + 0] += bflo2f(u.x);
            acc[j4 * 4 + 1] += bfhi2f(u.x);
            acc[j4 * 4 + 2] += bflo2f(u.y);
            acc[j4 * 4 + 3] += bfhi2f(u.y);
        }
    }
#pragma unroll
    for (int j = 0; j < 16; j++) trans[cg + j][m] = acc[j] * scale;
    __syncthreads();

    int c  = tid >> 2;
    int mg = (tid & 3) * 16;
    size_t idx = ((size_t)b * CC + cq * 64 + c) * NN + mt * 64 + mg;
#pragma unroll
    for (int j4 = 0; j4 < 4; j4++) {
        f32x4 xv = *(const f32x4*)(x + idx + j4 * 4);
        f32x4 o;
#pragma unroll
        for (int j = 0; j < 4; j++) o[j] = trans[c][mg + j4 * 4 + j] + xv[j];
        *(f32x4*)(out + idx + j4 * 4) = o;
    }
}

extern "C" void kernel_launch(void* const* d_in, const int* in_sizes, int n_in,
                              void* d_out, int out_size, void* d_ws, size_t ws_size,
                              hipStream_t stream) {
    const float* x     = (const float*)d_in[0];
    const float* Wq    = (const float*)d_in[1];
    const float* bq    = (const float*)d_in[2];
    const float* Wk    = (const float*)d_in[3];
    const float* bk    = (const float*)d_in[4];
    const float* Wv    = (const float*)d_in[5];
    const float* bv    = (const float*)d_in[6];
    const float* gamma = (const float*)d_in[7];
    float* out = (float*)d_out;
    (void)in_sizes; (void)n_in; (void)out_size;

    unsigned short* proj = (unsigned short*)d_ws;
    unsigned short* qT   = proj + (size_t)BN * PROJ_ROWS * NN;
    unsigned short* Wbf  = qT + (size_t)BN * NN * C8;
    const size_t baseB = ((size_t)BN * PROJ_ROWS * NN
                        + (size_t)BN * NN * C8
                        + (size_t)PROJ_ROWS * CC) * 2;

    auto needB = [&](size_t ns) {
        size_t LpB = ns * BN * 64 * 64 * 4;                  // fp32 L partials
        size_t OpB = ns * BN * 64 * (size_t)(64 * 256) * 2;  // bf16 O partials
        return baseB + LpB + OpB;
    };

    wcast_kernel<<<320, 256, 0, stream>>>(Wq, Wk, Wv, Wbf);
    proj_kernel<<<512, 256, 0, stream>>>(x, Wbf, bq, bk, bv, proj, qT);

    if (ws_size >= needB(2)) {
        float* Lpart = (float*)((char*)d_ws + baseB);
        unsigned short* Opart = (unsigned short*)(Lpart + (size_t)2 * BN * 64 * 64);
        attn_kernel<2, false><<<1024, 256, 0, stream>>>(proj, qT, x, gamma, out, Opart, Lpart);
        combine_kernel<2><<<1024, 256, 0, stream>>>(Opart, Lpart, x, gamma, out);
    } else {
        attn_kernel<1, true><<<512, 256, 0, stream>>>(proj, qT, x, gamma, out, nullptr, nullptr);
    }
}